// Round 2
// baseline (265.046 us; speedup 1.0000x reference)
//
#include <hip/hip_runtime.h>
#include <stdint.h>

typedef short short8 __attribute__((ext_vector_type(8)));
typedef float f32x4 __attribute__((ext_vector_type(4)));
typedef float f32x2 __attribute__((ext_vector_type(2)));

#define B_TOTAL 8192
#define DDIM 256
#define BM 128
#define BN 64
#define NSPLIT 16
#define COLS_PER (B_TOTAL / NSPLIT)   // 512
#define ITERS (COLS_PER / BN)         // 8
#define NBLOCKS ((B_TOTAL / BM) * NSPLIT)  // 1024
// sqrt((1/T)/ln2): fold temperature+log2e into the bf16 embeddings (both operands)
#define SCALE_HALF 3.79828546f
#define LN2F 0.6931471805599453f

typedef __attribute__((address_space(3))) char lds_char;
typedef __attribute__((address_space(1))) const char gbl_char;

__device__ __forceinline__ unsigned short f2bf(float f) {
  unsigned int u = __builtin_bit_cast(unsigned int, f);
  u = (u + 0x7FFFu + ((u >> 16) & 1u)) >> 16;   // RNE; inputs are finite
  return (unsigned short)u;
}

// ---- prep: fp32->bf16 (scaled), one-hot label pack, zero accumulators -------
__global__ __launch_bounds__(256) void prep_all(
    const float* __restrict__ E, const int* __restrict__ lab,
    unsigned short* __restrict__ Eb, unsigned int* __restrict__ plab,
    float* __restrict__ posAll, unsigned int* __restrict__ ctr) {
  const int t = blockIdx.x * 256 + threadIdx.x;   // 0..262143, 8 floats each
  const float4* s4 = (const float4*)E + (size_t)t * 2;
  float4 v0 = s4[0], v1 = s4[1];
  short8 o;
  o[0] = (short)f2bf(v0.x * SCALE_HALF); o[1] = (short)f2bf(v0.y * SCALE_HALF);
  o[2] = (short)f2bf(v0.z * SCALE_HALF); o[3] = (short)f2bf(v0.w * SCALE_HALF);
  o[4] = (short)f2bf(v1.x * SCALE_HALF); o[5] = (short)f2bf(v1.y * SCALE_HALF);
  o[6] = (short)f2bf(v1.z * SCALE_HALF); o[7] = (short)f2bf(v1.w * SCALE_HALF);
  *(short8*)(Eb + (size_t)t * 8) = o;
  if (t < B_TOTAL) {
    int4 l = ((const int4*)lab)[t];   // labels arrive as int32
    // positional one-hot: aspect a (value 0..5) occupies bits [6a, 6a+6)
    plab[t] = (1u << ((unsigned)l.x & 31u))
            | (1u << (((unsigned)l.y & 31u) + 6u))
            | (1u << (((unsigned)l.z & 31u) + 12u))
            | (1u << (((unsigned)l.w & 31u) + 18u));
  }
  if (t < 2 * B_TOTAL) posAll[t] = 0.0f;   // posArr+allArr contiguous
  if (t == 0) ctr[0] = 0u;
}

// ---- fused sim/exp/mask/rowsum + last-block loss reduction ------------------
struct __align__(16) SMem {
  char btile[BN * DDIM * 2];   // 32 KB, XOR-swizzled 16B chunks
  unsigned int plds[BN];
  float red[8];
  int lastFlag;
};

template <int DIAG>
__device__ __forceinline__ void do_epilogue(
    const f32x4 (&acc)[4][2], int colbase, int l15,
    const unsigned int (&pi)[2][4], const int (&irow)[2][4],
    const unsigned int* plds, f32x2 (&pos2)[2][2], f32x2 (&all2)[2][2]) {
#pragma unroll
  for (int n = 0; n < 4; ++n) {
    const int j = colbase + n * 16 + l15;
    const unsigned int hj = plds[n * 16 + l15];
#pragma unroll
    for (int m = 0; m < 2; ++m) {
      float e[4];
#pragma unroll
      for (int q = 0; q < 4; ++q) {
        float v = __builtin_amdgcn_exp2f(acc[n][m][q]);  // acc already scaled
        if (DIAG) { if (j == irow[m][q]) v = 0.0f; }
        e[q] = v;
      }
      f32x2 p01 = { (pi[m][0] & hj) ? e[0] : 0.0f, (pi[m][1] & hj) ? e[1] : 0.0f };
      f32x2 p23 = { (pi[m][2] & hj) ? e[2] : 0.0f, (pi[m][3] & hj) ? e[3] : 0.0f };
      all2[m][0] += (f32x2){e[0], e[1]};
      all2[m][1] += (f32x2){e[2], e[3]};
      pos2[m][0] += p01;
      pos2[m][1] += p23;
    }
  }
}

__global__ __launch_bounds__(256, 4) void main_kernel(
    const unsigned short* __restrict__ Eb, const unsigned int* __restrict__ plab,
    float* __restrict__ posArr, float* __restrict__ allArr,
    unsigned int* __restrict__ ctr, float* __restrict__ out) {
  __shared__ SMem sm;
  const int tid = threadIdx.x;
  const int lane = tid & 63;
  const int wid = tid >> 6;        // 4 waves, each owns 32 rows
  const int l15 = lane & 15;
  const int l4 = lane >> 4;
  const int rb = (int)blockIdx.x & 63;
  const int cs = (int)blockIdx.x >> 6;
  const int rowbase = rb * BM;
  const int colstart = cs * COLS_PER;

  // A fragments: register-resident, 32 rows x 256 k per wave
  short8 afrag[2][8];
#pragma unroll
  for (int m = 0; m < 2; ++m) {
    const int row = rowbase + wid * 32 + m * 16 + l15;
    const unsigned short* rp = Eb + (size_t)row * DDIM + l4 * 8;
#pragma unroll
    for (int k = 0; k < 8; ++k) afrag[m][k] = *(const short8*)(rp + k * 32);
  }

  unsigned int pi[2][4];
  int irow[2][4];
#pragma unroll
  for (int m = 0; m < 2; ++m)
#pragma unroll
    for (int q = 0; q < 4; ++q) {
      const int i = rowbase + wid * 32 + m * 16 + l4 * 4 + q;
      irow[m][q] = i;
      pi[m][q] = plab[i];
    }

  f32x2 pos2[2][2] = {};
  f32x2 all2[2][2] = {};

  for (int it = 0; it < ITERS; ++it) {
    const int colbase = colstart + it * BN;
    __syncthreads();   // previous iter's LDS reads done
    // stage B tile: linear LDS dest, inverse-swizzled global source (rule #21)
#pragma unroll
    for (int q = 0; q < 8; ++q) {
      const unsigned int L = (unsigned int)wid * 8192u + (unsigned int)q * 1024u +
                             (unsigned int)lane * 16u;
      const unsigned int r = L >> 9;          // B-tile row (0..63)
      const unsigned int s = (L >> 4) & 31u;  // stored 16B chunk in row
      const unsigned int c = s ^ (r & 7u);    // logical chunk (involution)
      const char* src = (const char*)(Eb + (size_t)(colbase + (int)r) * DDIM + c * 8);
      char* dst = sm.btile + (unsigned int)wid * 8192u + (unsigned int)q * 1024u;
      __builtin_amdgcn_global_load_lds((gbl_char*)src, (lds_char*)dst, 16, 0, 0);
    }
    if (tid < BN) sm.plds[tid] = plab[colbase + tid];
    __syncthreads();   // staging visible (syncthreads drains vmcnt)

    f32x4 acc[4][2];
#pragma unroll
    for (int n = 0; n < 4; ++n)
#pragma unroll
      for (int m = 0; m < 2; ++m) acc[n][m] = (f32x4){0.f, 0.f, 0.f, 0.f};

#pragma unroll
    for (int k = 0; k < 8; ++k) {
      short8 b[4];
#pragma unroll
      for (int n = 0; n < 4; ++n) {
        const unsigned int rr = (unsigned int)(n * 16 + l15);
        const unsigned int cdx = (unsigned int)(k * 4 + l4);
        const unsigned int s = cdx ^ (rr & 7u);   // swizzled read
        b[n] = *(const short8*)(sm.btile + rr * 512u + s * 16u);
      }
#pragma unroll
      for (int n = 0; n < 4; ++n)
#pragma unroll
        for (int m = 0; m < 2; ++m)
          acc[n][m] = __builtin_amdgcn_mfma_f32_16x16x32_bf16(
              afrag[m][k], b[n], acc[n][m], 0, 0, 0);
    }

    const bool hasDiag = (colbase < rowbase + BM) && (rowbase < colbase + BN);
    if (hasDiag)
      do_epilogue<1>(acc, colbase, l15, pi, irow, sm.plds, pos2, all2);
    else
      do_epilogue<0>(acc, colbase, l15, pi, irow, sm.plds, pos2, all2);
  }

  // reduce across the 16 lanes sharing the same rows, then one atomic per row
#pragma unroll
  for (int m = 0; m < 2; ++m)
#pragma unroll
    for (int q = 0; q < 4; ++q) {
      float p = pos2[m][q >> 1][q & 1], al = all2[m][q >> 1][q & 1];
      p += __shfl_xor(p, 1); p += __shfl_xor(p, 2);
      p += __shfl_xor(p, 4); p += __shfl_xor(p, 8);
      al += __shfl_xor(al, 1); al += __shfl_xor(al, 2);
      al += __shfl_xor(al, 4); al += __shfl_xor(al, 8);
      if (l15 == 0) {
        atomicAdd(&posArr[irow[m][q]], p);
        atomicAdd(&allArr[irow[m][q]], al);
      }
    }

  // ---- last block computes the final loss (replaces finalize kernel) -------
  __threadfence();
  if (tid == 0) {
    unsigned int t = __hip_atomic_fetch_add(ctr, 1u, __ATOMIC_ACQ_REL,
                                            __HIP_MEMORY_SCOPE_AGENT);
    sm.lastFlag = (t == NBLOCKS - 1);
  }
  __syncthreads();
  if (!sm.lastFlag) return;

  float ls = 0.f, cnt = 0.f;
#pragma unroll
  for (int k = 0; k < B_TOTAL / 256; ++k) {
    const int i = tid + (k << 8);
    const float p = __hip_atomic_load(&posArr[i], __ATOMIC_RELAXED,
                                      __HIP_MEMORY_SCOPE_AGENT);
    const float a = __hip_atomic_load(&allArr[i], __ATOMIC_RELAXED,
                                      __HIP_MEMORY_SCOPE_AGENT);
    if (p > 0.f) {
      ls += (__builtin_amdgcn_logf(a + 1e-8f) - __builtin_amdgcn_logf(p)) * LN2F;
      cnt += 1.f;
    }
  }
#pragma unroll
  for (int msk = 1; msk < 64; msk <<= 1) {
    ls += __shfl_xor(ls, msk);
    cnt += __shfl_xor(cnt, msk);
  }
  if (lane == 0) { sm.red[wid] = ls; sm.red[4 + wid] = cnt; }
  __syncthreads();
  if (tid == 0) {
    float L = sm.red[0] + sm.red[1] + sm.red[2] + sm.red[3];
    float C = sm.red[4] + sm.red[5] + sm.red[6] + sm.red[7];
    out[0] = (C > 0.f) ? L / fmaxf(C, 1.f) : 0.f;
  }
}

// ---- launch -----------------------------------------------------------------
extern "C" void kernel_launch(void* const* d_in, const int* in_sizes, int n_in,
                              void* d_out, int out_size, void* d_ws, size_t ws_size,
                              hipStream_t stream) {
  const float* E = (const float*)d_in[0];
  const int* lab = (const int*)d_in[1];
  float* out = (float*)d_out;
  char* ws = (char*)d_ws;

  unsigned short* Eb = (unsigned short*)ws;                       // 4 MB
  unsigned int* plab = (unsigned int*)(ws + 4u * 1024u * 1024u);  // 32 KB
  float* posArr = (float*)(ws + 4u * 1024u * 1024u + 32u * 1024u);
  float* allArr = posArr + B_TOTAL;
  unsigned int* ctr = (unsigned int*)(allArr + B_TOTAL);

  prep_all<<<1024, 256, 0, stream>>>(E, lab, Eb, plab, posArr, ctr);
  main_kernel<<<NBLOCKS, 256, 0, stream>>>(Eb, plab, posArr, allArr, ctr, out);
}

// Round 3
// 176.658 us; speedup vs baseline: 1.5003x; 1.5003x over previous
//
#include <hip/hip_runtime.h>
#include <stdint.h>

typedef short short8 __attribute__((ext_vector_type(8)));
typedef float f32x4 __attribute__((ext_vector_type(4)));
typedef float f32x2 __attribute__((ext_vector_type(2)));

#define B_TOTAL 8192
#define DDIM 256
#define BM 128
#define BN 64
#define NSPLIT 16
#define COLS_PER (B_TOTAL / NSPLIT)   // 512
#define ITERS (COLS_PER / BN)         // 8
#define NBLOCKS ((B_TOTAL / BM) * NSPLIT)  // 1024
// sqrt((1/T)/ln2): fold temperature+log2e into the bf16 embeddings (both operands)
#define SCALE_HALF 3.79828546f
#define LN2F 0.6931471805599453f

typedef __attribute__((address_space(3))) char lds_char;
typedef __attribute__((address_space(1))) const char gbl_char;

__device__ __forceinline__ unsigned short f2bf(float f) {
  unsigned int u = __builtin_bit_cast(unsigned int, f);
  u = (u + 0x7FFFu + ((u >> 16) & 1u)) >> 16;   // RNE; inputs are finite
  return (unsigned short)u;
}

// ---- prep: fp32->bf16 (scaled), one-hot label pack, zero accumulators -------
__global__ __launch_bounds__(256) void prep_all(
    const float* __restrict__ E, const int* __restrict__ lab,
    unsigned short* __restrict__ Eb, unsigned int* __restrict__ plab,
    float* __restrict__ posAll, unsigned int* __restrict__ ctr) {
  const int t = blockIdx.x * 256 + threadIdx.x;   // 0..262143, 8 floats each
  const float4* s4 = (const float4*)E + (size_t)t * 2;
  float4 v0 = s4[0], v1 = s4[1];
  short8 o;
  o[0] = (short)f2bf(v0.x * SCALE_HALF); o[1] = (short)f2bf(v0.y * SCALE_HALF);
  o[2] = (short)f2bf(v0.z * SCALE_HALF); o[3] = (short)f2bf(v0.w * SCALE_HALF);
  o[4] = (short)f2bf(v1.x * SCALE_HALF); o[5] = (short)f2bf(v1.y * SCALE_HALF);
  o[6] = (short)f2bf(v1.z * SCALE_HALF); o[7] = (short)f2bf(v1.w * SCALE_HALF);
  *(short8*)(Eb + (size_t)t * 8) = o;
  if (t < B_TOTAL) {
    int4 l = ((const int4*)lab)[t];   // labels arrive as int32
    // positional one-hot: aspect a (value 0..5) occupies bits [6a, 6a+6)
    plab[t] = (1u << ((unsigned)l.x & 31u))
            | (1u << (((unsigned)l.y & 31u) + 6u))
            | (1u << (((unsigned)l.z & 31u) + 12u))
            | (1u << (((unsigned)l.w & 31u) + 18u));
  }
  if (t < 2 * B_TOTAL) posAll[t] = 0.0f;   // posArr+allArr contiguous
  if (t == 0) ctr[0] = 0u;
}

// ---- fused sim/exp/mask/rowsum + last-block loss reduction ------------------
struct __align__(16) SMem {
  char btile[BN * DDIM * 2];   // 32 KB, XOR-swizzled 16B chunks
  unsigned int plds[BN];
  float red[8];
  int lastFlag;
};

template <int DIAG>
__device__ __forceinline__ void do_epilogue(
    const f32x4 (&acc)[4][2], int colbase, int l15,
    const unsigned int (&pi)[2][4], const int (&irow)[2][4],
    const unsigned int* plds, f32x2 (&pos2)[2][2], f32x2 (&all2)[2][2]) {
#pragma unroll
  for (int n = 0; n < 4; ++n) {
    const int j = colbase + n * 16 + l15;
    const unsigned int hj = plds[n * 16 + l15];
#pragma unroll
    for (int m = 0; m < 2; ++m) {
      float e[4];
#pragma unroll
      for (int q = 0; q < 4; ++q) {
        float v = __builtin_amdgcn_exp2f(acc[n][m][q]);  // acc already scaled
        if (DIAG) { if (j == irow[m][q]) v = 0.0f; }
        e[q] = v;
      }
      f32x2 p01 = { (pi[m][0] & hj) ? e[0] : 0.0f, (pi[m][1] & hj) ? e[1] : 0.0f };
      f32x2 p23 = { (pi[m][2] & hj) ? e[2] : 0.0f, (pi[m][3] & hj) ? e[3] : 0.0f };
      all2[m][0] += (f32x2){e[0], e[1]};
      all2[m][1] += (f32x2){e[2], e[3]};
      pos2[m][0] += p01;
      pos2[m][1] += p23;
    }
  }
}

__global__ __launch_bounds__(256, 2) void main_kernel(
    const unsigned short* __restrict__ Eb, const unsigned int* __restrict__ plab,
    float* __restrict__ posArr, float* __restrict__ allArr,
    unsigned int* __restrict__ ctr, float* __restrict__ out) {
  __shared__ SMem sm;
  const int tid = threadIdx.x;
  const int lane = tid & 63;
  const int wid = tid >> 6;        // 4 waves, each owns 32 rows
  const int l15 = lane & 15;
  const int l4 = lane >> 4;
  const int rb = (int)blockIdx.x & 63;
  const int cs = (int)blockIdx.x >> 6;
  const int rowbase = rb * BM;
  const int colstart = cs * COLS_PER;

  // A fragments: register-resident, 32 rows x 256 k per wave
  short8 afrag[2][8];
#pragma unroll
  for (int m = 0; m < 2; ++m) {
    const int row = rowbase + wid * 32 + m * 16 + l15;
    const unsigned short* rp = Eb + (size_t)row * DDIM + l4 * 8;
#pragma unroll
    for (int k = 0; k < 8; ++k) afrag[m][k] = *(const short8*)(rp + k * 32);
  }

  unsigned int pi[2][4];
  int irow[2][4];
#pragma unroll
  for (int m = 0; m < 2; ++m)
#pragma unroll
    for (int q = 0; q < 4; ++q) {
      const int i = rowbase + wid * 32 + m * 16 + l4 * 4 + q;
      irow[m][q] = i;
      pi[m][q] = plab[i];
    }

  f32x2 pos2[2][2] = {};
  f32x2 all2[2][2] = {};

  for (int it = 0; it < ITERS; ++it) {
    const int colbase = colstart + it * BN;
    __syncthreads();   // previous iter's LDS reads done
    // stage B tile: linear LDS dest, inverse-swizzled global source (rule #21)
#pragma unroll
    for (int q = 0; q < 8; ++q) {
      const unsigned int L = (unsigned int)wid * 8192u + (unsigned int)q * 1024u +
                             (unsigned int)lane * 16u;
      const unsigned int r = L >> 9;          // B-tile row (0..63)
      const unsigned int s = (L >> 4) & 31u;  // stored 16B chunk in row
      const unsigned int c = s ^ (r & 7u);    // logical chunk (involution)
      const char* src = (const char*)(Eb + (size_t)(colbase + (int)r) * DDIM + c * 8);
      char* dst = sm.btile + (unsigned int)wid * 8192u + (unsigned int)q * 1024u;
      __builtin_amdgcn_global_load_lds((gbl_char*)src, (lds_char*)dst, 16, 0, 0);
    }
    if (tid < BN) sm.plds[tid] = plab[colbase + tid];
    __syncthreads();   // staging visible (syncthreads drains vmcnt)

    f32x4 acc[4][2];
#pragma unroll
    for (int n = 0; n < 4; ++n)
#pragma unroll
      for (int m = 0; m < 2; ++m) acc[n][m] = (f32x4){0.f, 0.f, 0.f, 0.f};

#pragma unroll
    for (int k = 0; k < 8; ++k) {
      short8 b[4];
#pragma unroll
      for (int n = 0; n < 4; ++n) {
        const unsigned int rr = (unsigned int)(n * 16 + l15);
        const unsigned int cdx = (unsigned int)(k * 4 + l4);
        const unsigned int s = cdx ^ (rr & 7u);   // swizzled read
        b[n] = *(const short8*)(sm.btile + rr * 512u + s * 16u);
      }
#pragma unroll
      for (int n = 0; n < 4; ++n)
#pragma unroll
        for (int m = 0; m < 2; ++m)
          acc[n][m] = __builtin_amdgcn_mfma_f32_16x16x32_bf16(
              afrag[m][k], b[n], acc[n][m], 0, 0, 0);
    }

    const bool hasDiag = (colbase < rowbase + BM) && (rowbase < colbase + BN);
    if (hasDiag)
      do_epilogue<1>(acc, colbase, l15, pi, irow, sm.plds, pos2, all2);
    else
      do_epilogue<0>(acc, colbase, l15, pi, irow, sm.plds, pos2, all2);
  }

  // reduce across the 16 lanes sharing the same rows, then one atomic per row
#pragma unroll
  for (int m = 0; m < 2; ++m)
#pragma unroll
    for (int q = 0; q < 4; ++q) {
      float p = pos2[m][q >> 1][q & 1], al = all2[m][q >> 1][q & 1];
      p += __shfl_xor(p, 1); p += __shfl_xor(p, 2);
      p += __shfl_xor(p, 4); p += __shfl_xor(p, 8);
      al += __shfl_xor(al, 1); al += __shfl_xor(al, 2);
      al += __shfl_xor(al, 4); al += __shfl_xor(al, 8);
      if (l15 == 0) {
        atomicAdd(&posArr[irow[m][q]], p);
        atomicAdd(&allArr[irow[m][q]], al);
      }
    }

  // ---- last block computes the final loss (replaces finalize kernel) -------
  __threadfence();
  if (tid == 0) {
    unsigned int t = __hip_atomic_fetch_add(ctr, 1u, __ATOMIC_ACQ_REL,
                                            __HIP_MEMORY_SCOPE_AGENT);
    sm.lastFlag = (t == NBLOCKS - 1);
  }
  __syncthreads();
  if (!sm.lastFlag) return;

  float ls = 0.f, cnt = 0.f;
#pragma unroll
  for (int k = 0; k < B_TOTAL / 256; ++k) {
    const int i = tid + (k << 8);
    const float p = __hip_atomic_load(&posArr[i], __ATOMIC_RELAXED,
                                      __HIP_MEMORY_SCOPE_AGENT);
    const float a = __hip_atomic_load(&allArr[i], __ATOMIC_RELAXED,
                                      __HIP_MEMORY_SCOPE_AGENT);
    if (p > 0.f) {
      ls += (__builtin_amdgcn_logf(a + 1e-8f) - __builtin_amdgcn_logf(p)) * LN2F;
      cnt += 1.f;
    }
  }
#pragma unroll
  for (int msk = 1; msk < 64; msk <<= 1) {
    ls += __shfl_xor(ls, msk);
    cnt += __shfl_xor(cnt, msk);
  }
  if (lane == 0) { sm.red[wid] = ls; sm.red[4 + wid] = cnt; }
  __syncthreads();
  if (tid == 0) {
    float L = sm.red[0] + sm.red[1] + sm.red[2] + sm.red[3];
    float C = sm.red[4] + sm.red[5] + sm.red[6] + sm.red[7];
    out[0] = (C > 0.f) ? L / fmaxf(C, 1.f) : 0.f;
  }
}

// ---- launch -----------------------------------------------------------------
extern "C" void kernel_launch(void* const* d_in, const int* in_sizes, int n_in,
                              void* d_out, int out_size, void* d_ws, size_t ws_size,
                              hipStream_t stream) {
  const float* E = (const float*)d_in[0];
  const int* lab = (const int*)d_in[1];
  float* out = (float*)d_out;
  char* ws = (char*)d_ws;

  unsigned short* Eb = (unsigned short*)ws;                       // 4 MB
  unsigned int* plab = (unsigned int*)(ws + 4u * 1024u * 1024u);  // 32 KB
  float* posArr = (float*)(ws + 4u * 1024u * 1024u + 32u * 1024u);
  float* allArr = posArr + B_TOTAL;
  unsigned int* ctr = (unsigned int*)(allArr + B_TOTAL);

  prep_all<<<1024, 256, 0, stream>>>(E, lab, Eb, plab, posArr, ctr);
  main_kernel<<<NBLOCKS, 256, 0, stream>>>(Eb, plab, posArr, allArr, ctr, out);
}

// Round 4
// 110.718 us; speedup vs baseline: 2.3939x; 1.5956x over previous
//
#include <hip/hip_runtime.h>
#include <stdint.h>

typedef short short8 __attribute__((ext_vector_type(8)));
typedef float f32x4 __attribute__((ext_vector_type(4)));
typedef float f32x2 __attribute__((ext_vector_type(2)));

#define B_TOTAL 8192
#define DDIM 256
#define BM 128
#define BN 64
#define NSPLIT 16
#define COLS_PER (B_TOTAL / NSPLIT)   // 512
#define ITERS (COLS_PER / BN)         // 8
#define NBLOCKS ((B_TOTAL / BM) * NSPLIT)  // 1024
// sqrt((1/T)/ln2): fold temperature+log2e into the bf16 embeddings (both operands)
#define SCALE_HALF 3.79828546f
#define LN2F 0.6931471805599453f

typedef __attribute__((address_space(3))) char lds_char;
typedef __attribute__((address_space(1))) const char gbl_char;

__device__ __forceinline__ unsigned short f2bf(float f) {
  unsigned int u = __builtin_bit_cast(unsigned int, f);
  u = (u + 0x7FFFu + ((u >> 16) & 1u)) >> 16;   // RNE; inputs are finite
  return (unsigned short)u;
}

// ---- prep: fp32->bf16 (scaled), one-hot label pack, zero accumulators -------
__global__ __launch_bounds__(256) void prep_all(
    const float* __restrict__ E, const int* __restrict__ lab,
    unsigned short* __restrict__ Eb, unsigned int* __restrict__ plab,
    float* __restrict__ posAll) {
  const int t = blockIdx.x * 256 + threadIdx.x;   // 0..262143, 8 floats each
  const float4* s4 = (const float4*)E + (size_t)t * 2;
  float4 v0 = s4[0], v1 = s4[1];
  short8 o;
  o[0] = (short)f2bf(v0.x * SCALE_HALF); o[1] = (short)f2bf(v0.y * SCALE_HALF);
  o[2] = (short)f2bf(v0.z * SCALE_HALF); o[3] = (short)f2bf(v0.w * SCALE_HALF);
  o[4] = (short)f2bf(v1.x * SCALE_HALF); o[5] = (short)f2bf(v1.y * SCALE_HALF);
  o[6] = (short)f2bf(v1.z * SCALE_HALF); o[7] = (short)f2bf(v1.w * SCALE_HALF);
  *(short8*)(Eb + (size_t)t * 8) = o;
  if (t < B_TOTAL) {
    int4 l = ((const int4*)lab)[t];   // labels arrive as int32
    // positional one-hot: aspect a (value 0..5) occupies bits [6a, 6a+6)
    plab[t] = (1u << ((unsigned)l.x & 31u))
            | (1u << (((unsigned)l.y & 31u) + 6u))
            | (1u << (((unsigned)l.z & 31u) + 12u))
            | (1u << (((unsigned)l.w & 31u) + 18u));
  }
  if (t < 2 * B_TOTAL) posAll[t] = 0.0f;   // posArr+allArr contiguous
}

// ---- fused sim/exp/mask/rowsum ----------------------------------------------
struct __align__(16) SMem {
  char btile[BN * DDIM * 2];   // 32 KB, XOR-swizzled 16B chunks
  unsigned int plds[BN];
};

template <int DIAG>
__device__ __forceinline__ void do_epilogue(
    const f32x4 (&acc)[4][2], int colbase, int l15,
    const unsigned int (&pi)[2][4], const int (&irow)[2][4],
    const unsigned int* plds, f32x2 (&pos2)[2][2], f32x2 (&all2)[2][2]) {
#pragma unroll
  for (int n = 0; n < 4; ++n) {
    const int j = colbase + n * 16 + l15;
    const unsigned int hj = plds[n * 16 + l15];
#pragma unroll
    for (int m = 0; m < 2; ++m) {
      float e[4];
#pragma unroll
      for (int q = 0; q < 4; ++q) {
        float v = __builtin_amdgcn_exp2f(acc[n][m][q]);  // acc already scaled
        if (DIAG) { if (j == irow[m][q]) v = 0.0f; }
        e[q] = v;
      }
      f32x2 p01 = { (pi[m][0] & hj) ? e[0] : 0.0f, (pi[m][1] & hj) ? e[1] : 0.0f };
      f32x2 p23 = { (pi[m][2] & hj) ? e[2] : 0.0f, (pi[m][3] & hj) ? e[3] : 0.0f };
      all2[m][0] += (f32x2){e[0], e[1]};
      all2[m][1] += (f32x2){e[2], e[3]};
      pos2[m][0] += p01;
      pos2[m][1] += p23;
    }
  }
}

__global__ __launch_bounds__(256, 2) void main_kernel(
    const unsigned short* __restrict__ Eb, const unsigned int* __restrict__ plab,
    float* __restrict__ posArr, float* __restrict__ allArr) {
  __shared__ SMem sm;
  const int tid = threadIdx.x;
  const int lane = tid & 63;
  const int wid = tid >> 6;        // 4 waves, each owns 32 rows
  const int l15 = lane & 15;
  const int l4 = lane >> 4;
  const int rb = (int)blockIdx.x & 63;
  const int cs = (int)blockIdx.x >> 6;
  const int rowbase = rb * BM;
  const int colstart = cs * COLS_PER;

  // A fragments: register-resident, 32 rows x 256 k per wave
  short8 afrag[2][8];
#pragma unroll
  for (int m = 0; m < 2; ++m) {
    const int row = rowbase + wid * 32 + m * 16 + l15;
    const unsigned short* rp = Eb + (size_t)row * DDIM + l4 * 8;
#pragma unroll
    for (int k = 0; k < 8; ++k) afrag[m][k] = *(const short8*)(rp + k * 32);
  }

  unsigned int pi[2][4];
  int irow[2][4];
#pragma unroll
  for (int m = 0; m < 2; ++m)
#pragma unroll
    for (int q = 0; q < 4; ++q) {
      const int i = rowbase + wid * 32 + m * 16 + l4 * 4 + q;
      irow[m][q] = i;
      pi[m][q] = plab[i];
    }

  f32x2 pos2[2][2] = {};
  f32x2 all2[2][2] = {};

  for (int it = 0; it < ITERS; ++it) {
    const int colbase = colstart + it * BN;
    __syncthreads();   // previous iter's LDS reads done
    // stage B tile: linear LDS dest, inverse-swizzled global source (rule #21)
#pragma unroll
    for (int q = 0; q < 8; ++q) {
      const unsigned int L = (unsigned int)wid * 8192u + (unsigned int)q * 1024u +
                             (unsigned int)lane * 16u;
      const unsigned int r = L >> 9;          // B-tile row (0..63)
      const unsigned int s = (L >> 4) & 31u;  // stored 16B chunk in row
      const unsigned int c = s ^ (r & 7u);    // logical chunk (involution)
      const char* src = (const char*)(Eb + (size_t)(colbase + (int)r) * DDIM + c * 8);
      char* dst = sm.btile + (unsigned int)wid * 8192u + (unsigned int)q * 1024u;
      __builtin_amdgcn_global_load_lds((gbl_char*)src, (lds_char*)dst, 16, 0, 0);
    }
    if (tid < BN) sm.plds[tid] = plab[colbase + tid];
    __syncthreads();   // staging visible (syncthreads drains vmcnt)

    f32x4 acc[4][2];
#pragma unroll
    for (int n = 0; n < 4; ++n)
#pragma unroll
      for (int m = 0; m < 2; ++m) acc[n][m] = (f32x4){0.f, 0.f, 0.f, 0.f};

#pragma unroll
    for (int k = 0; k < 8; ++k) {
      short8 b[4];
#pragma unroll
      for (int n = 0; n < 4; ++n) {
        const unsigned int rr = (unsigned int)(n * 16 + l15);
        const unsigned int cdx = (unsigned int)(k * 4 + l4);
        const unsigned int s = cdx ^ (rr & 7u);   // swizzled read
        b[n] = *(const short8*)(sm.btile + rr * 512u + s * 16u);
      }
#pragma unroll
      for (int n = 0; n < 4; ++n)
#pragma unroll
        for (int m = 0; m < 2; ++m)
          acc[n][m] = __builtin_amdgcn_mfma_f32_16x16x32_bf16(
              afrag[m][k], b[n], acc[n][m], 0, 0, 0);
    }

    const bool hasDiag = (colbase < rowbase + BM) && (rowbase < colbase + BN);
    if (hasDiag)
      do_epilogue<1>(acc, colbase, l15, pi, irow, sm.plds, pos2, all2);
    else
      do_epilogue<0>(acc, colbase, l15, pi, irow, sm.plds, pos2, all2);
  }

  // reduce across the 16 lanes sharing the same rows, then one atomic per row
#pragma unroll
  for (int m = 0; m < 2; ++m)
#pragma unroll
    for (int q = 0; q < 4; ++q) {
      float p = pos2[m][q >> 1][q & 1], al = all2[m][q >> 1][q & 1];
      p += __shfl_xor(p, 1); p += __shfl_xor(p, 2);
      p += __shfl_xor(p, 4); p += __shfl_xor(p, 8);
      al += __shfl_xor(al, 1); al += __shfl_xor(al, 2);
      al += __shfl_xor(al, 4); al += __shfl_xor(al, 8);
      if (l15 == 0) {
        atomicAdd(&posArr[irow[m][q]], p);
        atomicAdd(&allArr[irow[m][q]], al);
      }
    }
}

// ---- finalize: row losses + mean (separate launch = free ordering) ----------
__global__ __launch_bounds__(1024) void finalize_kernel(
    const float* __restrict__ posArr, const float* __restrict__ allArr,
    float* __restrict__ out) {
  float ls = 0.f, cnt = 0.f;
#pragma unroll
  for (int k = 0; k < B_TOTAL / 1024; ++k) {
    const int i = threadIdx.x + (k << 10);
    const float p = posArr[i];
    const float a = allArr[i];
    if (p > 0.f) {
      ls += (__builtin_amdgcn_logf(a + 1e-8f) - __builtin_amdgcn_logf(p)) * LN2F;
      cnt += 1.f;
    }
  }
#pragma unroll
  for (int msk = 1; msk < 64; msk <<= 1) {
    ls += __shfl_xor(ls, msk);
    cnt += __shfl_xor(cnt, msk);
  }
  __shared__ float sls[16], scnt[16];
  const int w = threadIdx.x >> 6;
  if ((threadIdx.x & 63) == 0) { sls[w] = ls; scnt[w] = cnt; }
  __syncthreads();
  if (threadIdx.x == 0) {
    float L = 0.f, C = 0.f;
    for (int i = 0; i < 16; ++i) { L += sls[i]; C += scnt[i]; }
    out[0] = (C > 0.f) ? L / fmaxf(C, 1.f) : 0.f;
  }
}

// ---- launch -----------------------------------------------------------------
extern "C" void kernel_launch(void* const* d_in, const int* in_sizes, int n_in,
                              void* d_out, int out_size, void* d_ws, size_t ws_size,
                              hipStream_t stream) {
  const float* E = (const float*)d_in[0];
  const int* lab = (const int*)d_in[1];
  float* out = (float*)d_out;
  char* ws = (char*)d_ws;

  unsigned short* Eb = (unsigned short*)ws;                       // 4 MB
  unsigned int* plab = (unsigned int*)(ws + 4u * 1024u * 1024u);  // 32 KB
  float* posArr = (float*)(ws + 4u * 1024u * 1024u + 32u * 1024u);
  float* allArr = posArr + B_TOTAL;

  prep_all<<<1024, 256, 0, stream>>>(E, lab, Eb, plab, posArr);
  main_kernel<<<NBLOCKS, 256, 0, stream>>>(Eb, plab, posArr, allArr);
  finalize_kernel<<<1, 1024, 0, stream>>>(posArr, allArr, out);
}

// Round 5
// 108.919 us; speedup vs baseline: 2.4334x; 1.0165x over previous
//
#include <hip/hip_runtime.h>
#include <stdint.h>

typedef short short8 __attribute__((ext_vector_type(8)));
typedef float f32x4 __attribute__((ext_vector_type(4)));
typedef float f32x2 __attribute__((ext_vector_type(2)));

#define B_TOTAL 8192
#define DDIM 256
#define BM 128
#define BN 32
#define NSPLIT 16
#define COLS_PER (B_TOTAL / NSPLIT)        // 512
#define ITERS (COLS_PER / BN)              // 16
#define NBLOCKS ((B_TOTAL / BM) * NSPLIT)  // 1024
// sqrt((1/T)/ln2): fold temperature+log2e into the bf16 embeddings (both operands)
#define SCALE_HALF 3.79828546f
#define LN2F 0.6931471805599453f

typedef __attribute__((address_space(3))) char lds_char;
typedef __attribute__((address_space(1))) const char gbl_char;

__device__ __forceinline__ unsigned short f2bf(float f) {
  unsigned int u = __builtin_bit_cast(unsigned int, f);
  u = (u + 0x7FFFu + ((u >> 16) & 1u)) >> 16;   // RNE; inputs are finite
  return (unsigned short)u;
}

// ---- prep: fp32->bf16 (scaled), one-hot label pack, zero accumulators -------
__global__ __launch_bounds__(256) void prep_all(
    const float* __restrict__ E, const int* __restrict__ lab,
    unsigned short* __restrict__ Eb, unsigned int* __restrict__ plab,
    float* __restrict__ posAll) {
  const int t = blockIdx.x * 256 + threadIdx.x;   // 0..262143, 8 floats each
  const float4* s4 = (const float4*)E + (size_t)t * 2;
  float4 v0 = s4[0], v1 = s4[1];
  short8 o;
  o[0] = (short)f2bf(v0.x * SCALE_HALF); o[1] = (short)f2bf(v0.y * SCALE_HALF);
  o[2] = (short)f2bf(v0.z * SCALE_HALF); o[3] = (short)f2bf(v0.w * SCALE_HALF);
  o[4] = (short)f2bf(v1.x * SCALE_HALF); o[5] = (short)f2bf(v1.y * SCALE_HALF);
  o[6] = (short)f2bf(v1.z * SCALE_HALF); o[7] = (short)f2bf(v1.w * SCALE_HALF);
  *(short8*)(Eb + (size_t)t * 8) = o;
  if (t < B_TOTAL) {
    int4 l = ((const int4*)lab)[t];   // labels arrive as int32
    // positional one-hot: aspect a (value 0..5) occupies bits [6a, 6a+6)
    plab[t] = (1u << ((unsigned)l.x & 31u))
            | (1u << (((unsigned)l.y & 31u) + 6u))
            | (1u << (((unsigned)l.z & 31u) + 12u))
            | (1u << (((unsigned)l.w & 31u) + 18u));
  }
  if (t < 2 * B_TOTAL) posAll[t] = 0.0f;   // posArr+allArr contiguous
}

// ---- fused sim/exp/mask/rowsum, 2-phase double-buffered pipeline ------------
struct __align__(16) SMem {
  char btile[2][BN * DDIM * 2];      // 2 x 16 KB, XOR-swizzled 16B chunks
  unsigned int plab_all[COLS_PER];   // 2 KB: packed labels for the whole panel
};

template <int DIAG>
__device__ __forceinline__ void do_epilogue(
    const f32x4 (&acc)[2][2], int colbase, int it, int l15,
    const unsigned int (&pi)[2][4], const int (&irow)[2][4],
    const unsigned int* plab_all, f32x2 (&pos2)[2][2], f32x2 (&all2)[2][2]) {
#pragma unroll
  for (int n = 0; n < 2; ++n) {
    const int j = colbase + n * 16 + l15;
    const unsigned int hj = plab_all[it * BN + n * 16 + l15];
#pragma unroll
    for (int m = 0; m < 2; ++m) {
      float e[4];
#pragma unroll
      for (int q = 0; q < 4; ++q) {
        float v = __builtin_amdgcn_exp2f(acc[n][m][q]);  // acc already scaled
        if (DIAG) { if (j == irow[m][q]) v = 0.0f; }
        e[q] = v;
      }
      f32x2 p01 = { (pi[m][0] & hj) ? e[0] : 0.0f, (pi[m][1] & hj) ? e[1] : 0.0f };
      f32x2 p23 = { (pi[m][2] & hj) ? e[2] : 0.0f, (pi[m][3] & hj) ? e[3] : 0.0f };
      all2[m][0] += (f32x2){e[0], e[1]};
      all2[m][1] += (f32x2){e[2], e[3]};
      pos2[m][0] += p01;
      pos2[m][1] += p23;
    }
  }
}

__global__ __launch_bounds__(256, 2) void main_kernel(
    const unsigned short* __restrict__ Eb, const unsigned int* __restrict__ plab,
    float* __restrict__ posArr, float* __restrict__ allArr) {
  __shared__ SMem sm;
  const int tid = threadIdx.x;
  const int lane = tid & 63;
  const int wid = tid >> 6;        // 4 waves, each owns 32 rows
  const int l15 = lane & 15;
  const int l4 = lane >> 4;
  const int rb = (int)blockIdx.x & 63;
  const int cs = (int)blockIdx.x >> 6;
  const int rowbase = rb * BM;
  const int colstart = cs * COLS_PER;

  // stage helper: 16 KB tile, 4 x global_load_lds(16B) per wave.
  // linear LDS dest (wave-uniform base + lane*16), inverse-swizzled global src
  // (rule #21); read side applies the same XOR.
  auto stage = [&](int bufi, int cb) {
#pragma unroll
    for (int q = 0; q < 4; ++q) {
      const unsigned int L = (unsigned int)wid * 4096u + (unsigned int)q * 1024u +
                             (unsigned int)lane * 16u;
      const unsigned int r = L >> 9;          // B-tile row / output column (0..31)
      const unsigned int s = (L >> 4) & 31u;  // stored 16B chunk in row
      const unsigned int c = s ^ (r & 7u);    // logical chunk (involution)
      const char* src = (const char*)(Eb + (size_t)(cb + (int)r) * DDIM + c * 8);
      char* dst = sm.btile[bufi] + (unsigned int)wid * 4096u + (unsigned int)q * 1024u;
      __builtin_amdgcn_global_load_lds((gbl_char*)src, (lds_char*)dst, 16, 0, 0);
    }
  };

  // A fragments: register-resident, 32 rows x 256 k per wave
  short8 afrag[2][8];
#pragma unroll
  for (int m = 0; m < 2; ++m) {
    const int row = rowbase + wid * 32 + m * 16 + l15;
    const unsigned short* rp = Eb + (size_t)row * DDIM + l4 * 8;
#pragma unroll
    for (int k = 0; k < 8; ++k) afrag[m][k] = *(const short8*)(rp + k * 32);
  }

  // panel labels -> LDS once (keeps the in-loop vmcnt count pure: stage only)
  {
    unsigned int a0 = plab[colstart + tid];
    unsigned int a1 = plab[colstart + 256 + tid];
    sm.plab_all[tid] = a0;
    sm.plab_all[tid + 256] = a1;
  }

  unsigned int pi[2][4];
  int irow[2][4];
#pragma unroll
  for (int m = 0; m < 2; ++m)
#pragma unroll
    for (int q = 0; q < 4; ++q) {
      const int i = rowbase + wid * 32 + m * 16 + l4 * 4 + q;
      irow[m][q] = i;
      pi[m][q] = plab[i];
    }

  // prologue: stage tile 0 into buf 0; drain our ds_writes before first barrier
  stage(0, colstart);
  asm volatile("s_waitcnt lgkmcnt(0)" ::: "memory");
  __builtin_amdgcn_sched_barrier(0);

  f32x2 pos2[2][2] = {};
  f32x2 all2[2][2] = {};

  for (int it = 0; it < ITERS; ++it) {
    const int colbase = colstart + it * BN;
    const int cur = it & 1;

    if (it + 1 < ITERS) {
      stage(cur ^ 1, colbase + BN);                     // issue next tile (4/wave)
      asm volatile("s_waitcnt vmcnt(4)" ::: "memory");  // oldest 4 (tile it) landed
    } else {
      asm volatile("s_waitcnt vmcnt(0)" ::: "memory");  // final tile: full drain
    }
    __builtin_amdgcn_s_barrier();                       // all waves' shares landed
    __builtin_amdgcn_sched_barrier(0);

    f32x4 acc[2][2];
#pragma unroll
    for (int n = 0; n < 2; ++n)
#pragma unroll
      for (int m = 0; m < 2; ++m) acc[n][m] = (f32x4){0.f, 0.f, 0.f, 0.f};

#pragma unroll
    for (int k = 0; k < 8; ++k) {
      short8 b[2];
#pragma unroll
      for (int n = 0; n < 2; ++n) {
        const unsigned int rr = (unsigned int)(n * 16 + l15);
        const unsigned int cdx = (unsigned int)(k * 4 + l4);
        const unsigned int s = cdx ^ (rr & 7u);   // swizzled read
        b[n] = *(const short8*)(sm.btile[cur] + rr * 512u + s * 16u);
      }
#pragma unroll
      for (int n = 0; n < 2; ++n)
#pragma unroll
        for (int m = 0; m < 2; ++m)
          acc[n][m] = __builtin_amdgcn_mfma_f32_16x16x32_bf16(
              afrag[m][k], b[n], acc[n][m], 0, 0, 0);
    }

    const bool hasDiag = (colbase < rowbase + BM) && (rowbase < colbase + BN);
    if (hasDiag)
      do_epilogue<1>(acc, colbase, it, l15, pi, irow, sm.plab_all, pos2, all2);
    else
      do_epilogue<0>(acc, colbase, it, l15, pi, irow, sm.plab_all, pos2, all2);

    __builtin_amdgcn_s_barrier();   // all waves done reading btile[cur]
    __builtin_amdgcn_sched_barrier(0);
  }

  // reduce across the 16 lanes sharing the same rows, then one atomic per row
#pragma unroll
  for (int m = 0; m < 2; ++m)
#pragma unroll
    for (int q = 0; q < 4; ++q) {
      float p = pos2[m][q >> 1][q & 1], al = all2[m][q >> 1][q & 1];
      p += __shfl_xor(p, 1); p += __shfl_xor(p, 2);
      p += __shfl_xor(p, 4); p += __shfl_xor(p, 8);
      al += __shfl_xor(al, 1); al += __shfl_xor(al, 2);
      al += __shfl_xor(al, 4); al += __shfl_xor(al, 8);
      if (l15 == 0) {
        atomicAdd(&posArr[irow[m][q]], p);
        atomicAdd(&allArr[irow[m][q]], al);
      }
    }
}

// ---- finalize: row losses + mean (separate launch = free ordering) ----------
__global__ __launch_bounds__(1024) void finalize_kernel(
    const float* __restrict__ posArr, const float* __restrict__ allArr,
    float* __restrict__ out) {
  float ls = 0.f, cnt = 0.f;
#pragma unroll
  for (int k = 0; k < B_TOTAL / 1024; ++k) {
    const int i = threadIdx.x + (k << 10);
    const float p = posArr[i];
    const float a = allArr[i];
    if (p > 0.f) {
      ls += (__builtin_amdgcn_logf(a + 1e-8f) - __builtin_amdgcn_logf(p)) * LN2F;
      cnt += 1.f;
    }
  }
#pragma unroll
  for (int msk = 1; msk < 64; msk <<= 1) {
    ls += __shfl_xor(ls, msk);
    cnt += __shfl_xor(cnt, msk);
  }
  __shared__ float sls[16], scnt[16];
  const int w = threadIdx.x >> 6;
  if ((threadIdx.x & 63) == 0) { sls[w] = ls; scnt[w] = cnt; }
  __syncthreads();
  if (threadIdx.x == 0) {
    float L = 0.f, C = 0.f;
    for (int i = 0; i < 16; ++i) { L += sls[i]; C += scnt[i]; }
    out[0] = (C > 0.f) ? L / fmaxf(C, 1.f) : 0.f;
  }
}

// ---- launch -----------------------------------------------------------------
extern "C" void kernel_launch(void* const* d_in, const int* in_sizes, int n_in,
                              void* d_out, int out_size, void* d_ws, size_t ws_size,
                              hipStream_t stream) {
  const float* E = (const float*)d_in[0];
  const int* lab = (const int*)d_in[1];
  float* out = (float*)d_out;
  char* ws = (char*)d_ws;

  unsigned short* Eb = (unsigned short*)ws;                       // 4 MB
  unsigned int* plab = (unsigned int*)(ws + 4u * 1024u * 1024u);  // 32 KB
  float* posArr = (float*)(ws + 4u * 1024u * 1024u + 32u * 1024u);
  float* allArr = posArr + B_TOTAL;

  prep_all<<<1024, 256, 0, stream>>>(E, lab, Eb, plab, posArr);
  main_kernel<<<NBLOCKS, 256, 0, stream>>>(Eb, plab, posArr, allArr);
  finalize_kernel<<<1, 1024, 0, stream>>>(posArr, allArr, out);
}

// Round 6
// 108.672 us; speedup vs baseline: 2.4390x; 1.0023x over previous
//
#include <hip/hip_runtime.h>
#include <stdint.h>

typedef short short8 __attribute__((ext_vector_type(8)));
typedef float f32x4 __attribute__((ext_vector_type(4)));
typedef float f32x2 __attribute__((ext_vector_type(2)));

#define B_TOTAL 8192
#define DDIM 256
#define BM 128
#define BN 64
#define NSPLIT 16
#define COLS_PER (B_TOTAL / NSPLIT)        // 512
#define ITERS (COLS_PER / BN)              // 8
#define NBLOCKS ((B_TOTAL / BM) * NSPLIT)  // 1024
// sqrt((1/T)/ln2): fold temperature+log2e into the bf16 embeddings (both operands)
#define SCALE_HALF 3.79828546f
#define LN2F 0.6931471805599453f

typedef __attribute__((address_space(3))) char lds_char;
typedef __attribute__((address_space(1))) const char gbl_char;

__device__ __forceinline__ unsigned short f2bf(float f) {
  unsigned int u = __builtin_bit_cast(unsigned int, f);
  u = (u + 0x7FFFu + ((u >> 16) & 1u)) >> 16;   // RNE; inputs are finite
  return (unsigned short)u;
}

// ---- prep: fp32->bf16 (scaled), one-hot label pack, zero accumulators -------
__global__ __launch_bounds__(256) void prep_all(
    const float* __restrict__ E, const int* __restrict__ lab,
    unsigned short* __restrict__ Eb, unsigned int* __restrict__ plab,
    float* __restrict__ posAll) {
  const int t = blockIdx.x * 256 + threadIdx.x;   // 0..262143, 8 floats each
  const float4* s4 = (const float4*)E + (size_t)t * 2;
  float4 v0 = s4[0], v1 = s4[1];
  short8 o;
  o[0] = (short)f2bf(v0.x * SCALE_HALF); o[1] = (short)f2bf(v0.y * SCALE_HALF);
  o[2] = (short)f2bf(v0.z * SCALE_HALF); o[3] = (short)f2bf(v0.w * SCALE_HALF);
  o[4] = (short)f2bf(v1.x * SCALE_HALF); o[5] = (short)f2bf(v1.y * SCALE_HALF);
  o[6] = (short)f2bf(v1.z * SCALE_HALF); o[7] = (short)f2bf(v1.w * SCALE_HALF);
  *(short8*)(Eb + (size_t)t * 8) = o;
  if (t < B_TOTAL) {
    int4 l = ((const int4*)lab)[t];   // labels arrive as int32
    // positional one-hot: aspect a (value 0..5) occupies bits [6a, 6a+6)
    plab[t] = (1u << ((unsigned)l.x & 31u))
            | (1u << (((unsigned)l.y & 31u) + 6u))
            | (1u << (((unsigned)l.z & 31u) + 12u))
            | (1u << (((unsigned)l.w & 31u) + 18u));
  }
  if (t < 2 * B_TOTAL) posAll[t] = 0.0f;   // posArr+allArr contiguous
}

// ---- fused sim/exp/mask/rowsum, 2-phase dbuf, BN=64 windows -----------------
struct __align__(16) SMem {
  char btile[2][BN * DDIM * 2];      // 2 x 32 KB, XOR-swizzled 16B chunks
  unsigned int plab_all[COLS_PER];   // 2 KB: packed labels for the whole panel
};

template <int DIAG>
__device__ __forceinline__ void do_epilogue(
    const f32x4 (&acc)[4][2], int colbase, int it, int l15,
    const unsigned int (&pi)[2][4], const int (&irow)[2][4],
    const unsigned int* plab_all, f32x2 (&pos2)[2][2], f32x2 (&all2)[2][2]) {
#pragma unroll
  for (int n = 0; n < 4; ++n) {
    const int j = colbase + n * 16 + l15;
    const unsigned int hj = plab_all[it * BN + n * 16 + l15];
#pragma unroll
    for (int m = 0; m < 2; ++m) {
      float e[4];
#pragma unroll
      for (int q = 0; q < 4; ++q) {
        float v = __builtin_amdgcn_exp2f(acc[n][m][q]);  // acc already scaled
        if (DIAG) { if (j == irow[m][q]) v = 0.0f; }
        e[q] = v;
      }
      f32x2 p01 = { (pi[m][0] & hj) ? e[0] : 0.0f, (pi[m][1] & hj) ? e[1] : 0.0f };
      f32x2 p23 = { (pi[m][2] & hj) ? e[2] : 0.0f, (pi[m][3] & hj) ? e[3] : 0.0f };
      all2[m][0] += (f32x2){e[0], e[1]};
      all2[m][1] += (f32x2){e[2], e[3]};
      pos2[m][0] += p01;
      pos2[m][1] += p23;
    }
  }
}

__global__ __launch_bounds__(256, 2) void main_kernel(
    const unsigned short* __restrict__ Eb, const unsigned int* __restrict__ plab,
    float* __restrict__ posArr, float* __restrict__ allArr) {
  __shared__ SMem sm;
  const int tid = threadIdx.x;
  const int lane = tid & 63;
  const int wid = tid >> 6;        // 4 waves, each owns 32 rows
  const int l15 = lane & 15;
  const int l4 = lane >> 4;
  const int rb = (int)blockIdx.x & 63;
  const int cs = (int)blockIdx.x >> 6;
  const int rowbase = rb * BM;
  const int colstart = cs * COLS_PER;

  // stage helper: 32 KB tile, 8 x global_load_lds(16B) per thread.
  // linear LDS dest (wave-uniform base + lane*16), inverse-swizzled global src
  // (rule #21); read side applies the same XOR.
  auto stage = [&](int bufi, int cb) {
#pragma unroll
    for (int q = 0; q < 8; ++q) {
      const unsigned int L = (unsigned int)wid * 8192u + (unsigned int)q * 1024u +
                             (unsigned int)lane * 16u;
      const unsigned int r = L >> 9;          // B-tile row / output column (0..63)
      const unsigned int s = (L >> 4) & 31u;  // stored 16B chunk in row
      const unsigned int c = s ^ (r & 7u);    // logical chunk (involution)
      const char* src = (const char*)(Eb + (size_t)(cb + (int)r) * DDIM + c * 8);
      char* dst = sm.btile[bufi] + (unsigned int)wid * 8192u + (unsigned int)q * 1024u;
      __builtin_amdgcn_global_load_lds((gbl_char*)src, (lds_char*)dst, 16, 0, 0);
    }
  };

  // prologue: issue tile 0 staging first (hide L2 latency under setup below)
  stage(0, colstart);

  // A fragments: register-resident, 32 rows x 256 k per wave
  short8 afrag[2][8];
#pragma unroll
  for (int m = 0; m < 2; ++m) {
    const int row = rowbase + wid * 32 + m * 16 + l15;
    const unsigned short* rp = Eb + (size_t)row * DDIM + l4 * 8;
#pragma unroll
    for (int k = 0; k < 8; ++k) afrag[m][k] = *(const short8*)(rp + k * 32);
  }

  // panel labels -> LDS once (keeps the in-loop vmcnt count pure: stage only)
  {
    unsigned int a0 = plab[colstart + tid];
    unsigned int a1 = plab[colstart + 256 + tid];
    sm.plab_all[tid] = a0;
    sm.plab_all[tid + 256] = a1;
  }

  unsigned int pi[2][4];
  int irow[2][4];
#pragma unroll
  for (int m = 0; m < 2; ++m)
#pragma unroll
    for (int q = 0; q < 4; ++q) {
      const int i = rowbase + wid * 32 + m * 16 + l4 * 4 + q;
      irow[m][q] = i;
      pi[m][q] = plab[i];
    }

  // drain label ds_writes before first barrier (other waves read plab_all)
  asm volatile("s_waitcnt lgkmcnt(0)" ::: "memory");
  __builtin_amdgcn_sched_barrier(0);

  f32x2 pos2[2][2] = {};
  f32x2 all2[2][2] = {};

  for (int it = 0; it < ITERS; ++it) {
    const int colbase = colstart + it * BN;
    const int cur = it & 1;

    if (it + 1 < ITERS) {
      stage(cur ^ 1, colbase + BN);                     // issue next tile (8/thread)
      asm volatile("s_waitcnt vmcnt(8)" ::: "memory");  // oldest 8 (tile it) landed
    } else {
      asm volatile("s_waitcnt vmcnt(0)" ::: "memory");  // final tile: full drain
    }
    __builtin_amdgcn_s_barrier();                       // all waves' shares landed
    __builtin_amdgcn_sched_barrier(0);

    f32x4 acc[4][2];
#pragma unroll
    for (int n = 0; n < 4; ++n)
#pragma unroll
      for (int m = 0; m < 2; ++m) acc[n][m] = (f32x4){0.f, 0.f, 0.f, 0.f};

    __builtin_amdgcn_s_setprio(1);
#pragma unroll
    for (int k = 0; k < 8; ++k) {
      short8 b[4];
#pragma unroll
      for (int n = 0; n < 4; ++n) {
        const unsigned int rr = (unsigned int)(n * 16 + l15);
        const unsigned int cdx = (unsigned int)(k * 4 + l4);
        const unsigned int s = cdx ^ (rr & 7u);   // swizzled read
        b[n] = *(const short8*)(sm.btile[cur] + rr * 512u + s * 16u);
      }
#pragma unroll
      for (int n = 0; n < 4; ++n)
#pragma unroll
        for (int m = 0; m < 2; ++m)
          acc[n][m] = __builtin_amdgcn_mfma_f32_16x16x32_bf16(
              afrag[m][k], b[n], acc[n][m], 0, 0, 0);
    }
    __builtin_amdgcn_s_setprio(0);

    const bool hasDiag = (colbase < rowbase + BM) && (rowbase < colbase + BN);
    if (hasDiag)
      do_epilogue<1>(acc, colbase, it, l15, pi, irow, sm.plab_all, pos2, all2);
    else
      do_epilogue<0>(acc, colbase, it, l15, pi, irow, sm.plab_all, pos2, all2);

    __builtin_amdgcn_s_barrier();   // all waves done reading btile[cur]
    __builtin_amdgcn_sched_barrier(0);
  }

  // reduce across the 16 lanes sharing the same rows, then one atomic per row
#pragma unroll
  for (int m = 0; m < 2; ++m)
#pragma unroll
    for (int q = 0; q < 4; ++q) {
      float p = pos2[m][q >> 1][q & 1], al = all2[m][q >> 1][q & 1];
      p += __shfl_xor(p, 1); p += __shfl_xor(p, 2);
      p += __shfl_xor(p, 4); p += __shfl_xor(p, 8);
      al += __shfl_xor(al, 1); al += __shfl_xor(al, 2);
      al += __shfl_xor(al, 4); al += __shfl_xor(al, 8);
      if (l15 == 0) {
        atomicAdd(&posArr[irow[m][q]], p);
        atomicAdd(&allArr[irow[m][q]], al);
      }
    }
}

// ---- finalize: row losses + mean (separate launch = free ordering) ----------
__global__ __launch_bounds__(1024) void finalize_kernel(
    const float* __restrict__ posArr, const float* __restrict__ allArr,
    float* __restrict__ out) {
  float ls = 0.f, cnt = 0.f;
#pragma unroll
  for (int k = 0; k < B_TOTAL / 1024; ++k) {
    const int i = threadIdx.x + (k << 10);
    const float p = posArr[i];
    const float a = allArr[i];
    if (p > 0.f) {
      ls += (__builtin_amdgcn_logf(a + 1e-8f) - __builtin_amdgcn_logf(p)) * LN2F;
      cnt += 1.f;
    }
  }
#pragma unroll
  for (int msk = 1; msk < 64; msk <<= 1) {
    ls += __shfl_xor(ls, msk);
    cnt += __shfl_xor(cnt, msk);
  }
  __shared__ float sls[16], scnt[16];
  const int w = threadIdx.x >> 6;
  if ((threadIdx.x & 63) == 0) { sls[w] = ls; scnt[w] = cnt; }
  __syncthreads();
  if (threadIdx.x == 0) {
    float L = 0.f, C = 0.f;
    for (int i = 0; i < 16; ++i) { L += sls[i]; C += scnt[i]; }
    out[0] = (C > 0.f) ? L / fmaxf(C, 1.f) : 0.f;
  }
}

// ---- launch -----------------------------------------------------------------
extern "C" void kernel_launch(void* const* d_in, const int* in_sizes, int n_in,
                              void* d_out, int out_size, void* d_ws, size_t ws_size,
                              hipStream_t stream) {
  const float* E = (const float*)d_in[0];
  const int* lab = (const int*)d_in[1];
  float* out = (float*)d_out;
  char* ws = (char*)d_ws;

  unsigned short* Eb = (unsigned short*)ws;                       // 4 MB
  unsigned int* plab = (unsigned int*)(ws + 4u * 1024u * 1024u);  // 32 KB
  float* posArr = (float*)(ws + 4u * 1024u * 1024u + 32u * 1024u);
  float* allArr = posArr + B_TOTAL;

  prep_all<<<1024, 256, 0, stream>>>(E, lab, Eb, plab, posArr);
  main_kernel<<<NBLOCKS, 256, 0, stream>>>(Eb, plab, posArr, allArr);
  finalize_kernel<<<1, 1024, 0, stream>>>(posArr, allArr, out);
}